// Round 7
// baseline (42.268 us; speedup 1.0000x reference)
//
#include <hip/hip_runtime.h>
#include <hip/hip_bf16.h>
#include <math.h>

#define NB 8
#define NL 128
#define D_ATOM 256
#define DH 32       // d_hid
#define DAB 64      // 2*d_hid
#define K1 21
#define K2 30
#define KT 51       // K1+K2
#define ROWS (NB*NL) // 1024
#define LN_EPS 1e-5f

#define OUT1_ROW (NL*K1)      // 2688 floats
#define OUT2_ROW (NL*K2)      // 3840 floats
#define STAGE_N  (OUT1_ROW + OUT2_ROW) // 6528 floats

#define NTILES 104            // dk = d*52+k tiles: 1664/16
#define TL_STRIDE 2112        // per-row T_lds stride (u16): 32*64 + 4*16

typedef __attribute__((ext_vector_type(8))) short bf16x8;
typedef __attribute__((ext_vector_type(4))) float f32x4;

__device__ __forceinline__ unsigned short f2bf(float x) {
    __hip_bfloat16 h = __float2bfloat16(x);
    return *reinterpret_cast<unsigned short*>(&h);
}

// ---------------- Kernel 1: LN (blocks 0..255) + W-prep (blocks 256..268) ----
// (unchanged from round 6 — verified)
__global__ __launch_bounds__(256) void ln_wprep_kernel(
    const float* __restrict__ z, const float* __restrict__ W_in,
    const float* __restrict__ b_in, const float* __restrict__ ln_g,
    const float* __restrict__ ln_b, const float* __restrict__ W1,
    const float* __restrict__ W2, unsigned short* __restrict__ af,
    unsigned short* __restrict__ bbf, unsigned short* __restrict__ Wf)
{
    const int t = threadIdx.x;

    if (blockIdx.x >= 256) {
        const int base = ((int)blockIdx.x - 256) * 4096;
        #pragma unroll
        for (int e = 0; e < 16; ++e) {
            int widx = base + e * 256 + t;
            int nt = widx >> 9, lane = (widx >> 3) & 63, reg = widx & 7;
            int dk = nt * 16 + (lane & 15);
            int c  = ((lane >> 4) << 3) + reg;
            int d  = dk / 52, k = dk - d * 52;
            float v = 0.f;
            if (k < K1)      v = W1[(c * DH + d) * K1 + k];
            else if (k < KT) v = W2[(c * DH + d) * K2 + (k - K1)];
            Wf[widx] = f2bf(v);
        }
        return;
    }

    __shared__ float Wl[D_ATOM * DAB];   // 64 KB
    __shared__ float zl[4][D_ATOM];      // 4 KB
    const int w = t >> 6, j = t & 63;
    const int row0 = blockIdx.x * 4;

    #pragma unroll
    for (int s = 0; s < 16; ++s) {
        int i4 = t + s * 256;
        ((float4*)Wl)[i4] = ((const float4*)W_in)[i4];
    }
    ((float4*)zl)[t] = ((const float4*)(z + (size_t)row0 * D_ATOM))[t];
    __syncthreads();

    float acc = b_in[j];
    #pragma unroll 8
    for (int i = 0; i < D_ATOM; ++i)
        acc = fmaf(zl[w][i], Wl[i * DAB + j], acc);

    float g = 0.5f * acc * (1.0f + erff(acc * 0.70710678118654752f));

    float s = g, sq = g * g;
    #pragma unroll
    for (int msk = 1; msk < 64; msk <<= 1) {
        s  += __shfl_xor(s,  msk, 64);
        sq += __shfl_xor(sq, msk, 64);
    }
    float mu  = s  * (1.0f / 64.0f);
    float var = sq * (1.0f / 64.0f) - mu * mu;
    float y = (g - mu) * rsqrtf(var + LN_EPS) * ln_g[j] + ln_b[j];

    const int row = row0 + w;
    unsigned short hv = f2bf(y);
    if (j < DH) {
        const int c = j;
        af[((row >> 4) << 9) + ((((row & 15) | ((c >> 3) << 4)) << 3) | (c & 7))] = hv;
    } else {
        const int d = j - DH, m = row & 127, batch = row >> 7;
        bbf[batch * 4096 + ((m >> 4) << 9) +
            ((((m & 15) | ((d >> 3) << 4)) << 3) | (d & 7))] = hv;
    }
}

// ---------------- Kernel 2: fused T + pair (all-MFMA) ----------------
// 4 rows per block (256 blocks).
// Phase A: T = a @ W via MFMA over Wf ntiles; keep C rows 4j..4j+3 (j=B&3,
//          lane-group j), scatter bf16 to zero-padded T_lds[4][TL_STRIDE].
// Phase B (x2 halves): gather pair-B-frags from T_lds (conflict-free layout),
//          16 MFMA/wave against bb A-frags, stage 2 rows, coalesced copyout.
__global__ __launch_bounds__(256) void pair_fused_kernel(
    const unsigned short* __restrict__ af, const unsigned short* __restrict__ bbf,
    const unsigned short* __restrict__ Wf, const float* __restrict__ b1v,
    const float* __restrict__ b2v, float* __restrict__ out)
{
    const int B     = blockIdx.x;      // 0..255
    const int row0  = B * 4;
    const int batch = B >> 5;
    const int mt    = B >> 2;          // row-mtile in af
    const int jq    = B & 3;           // quarter within the mtile
    const int t     = threadIdx.x;
    const int w     = t >> 6, l = t & 63;
    const int lg    = l >> 4, li = l & 15;

    __shared__ unsigned short Tl[4 * TL_STRIDE];        // 16896 B
    __shared__ __align__(16) float stg[2][STAGE_N];     // 52224 B

    // zero-init Tl (pad entries k=52..63 must read as 0)
    for (int i = t; i < 4 * TL_STRIDE / 2; i += 256)
        ((unsigned int*)Tl)[i] = 0u;

    // own a-row A-frag + all 8 bb A-frags (register-resident)
    const bf16x8 a = ((const bf16x8*)af)[mt * 64 + l];
    bf16x8 afr[8];
    #pragma unroll
    for (int i = 0; i < 8; ++i)
        afr[i] = ((const bf16x8*)bbf)[batch * 512 + i * 64 + l];

    __syncthreads();

    // ---- phase A: T tiles ----
    #pragma unroll 2
    for (int i = 0; i < 26; ++i) {
        const int nt = w * 26 + i;
        const bf16x8 bw = ((const bf16x8*)Wf)[nt * 64 + l];
        f32x4 c = __builtin_amdgcn_mfma_f32_16x16x32_bf16(
            a, bw, (f32x4){0.f, 0.f, 0.f, 0.f}, 0, 0, 0);
        if (lg == jq) {
            const int dk = nt * 16 + li;
            const int d  = dk / 52;
            const int k  = dk - d * 52;
            const int base = d * 64 + ((d >> 3) << 4) + k;
            #pragma unroll
            for (int q = 0; q < 4; ++q)
                Tl[q * TL_STRIDE + base] = f2bf(c[q]);
        }
    }
    __syncthreads();

    float bias[4];
    #pragma unroll
    for (int kt = 0; kt < 4; ++kt) {
        int k = kt * 16 + li;
        bias[kt] = (k < K1) ? b1v[k] : (k < KT ? b2v[k - K1] : 0.f);
    }

    const int rloc = w >> 1;     // wave's row slot within the half
    const int mh   = w & 1;      // wave's m-half (4 mtiles)

    #pragma unroll
    for (int h = 0; h < 2; ++h) {
        const int rib = h * 2 + rloc;    // row in block, 0..3

        // gather pair-B-frags: lane l, reg jj -> d = lg*8+jj, k = kt*16+li
        bf16x8 bfr[4];
        #pragma unroll
        for (int kt = 0; kt < 4; ++kt) {
            union { unsigned short s[8]; bf16x8 v; } u;
            #pragma unroll
            for (int jj = 0; jj < 8; ++jj)
                u.s[jj] = Tl[rib * TL_STRIDE + (lg * 8 + jj) * 64 + (lg << 4)
                             + kt * 16 + li];
            bfr[kt] = u.v;
        }

        // 16 MFMA + scatter into stg[rloc]
        #pragma unroll
        for (int i = 0; i < 4; ++i) {
            const int mbase = (mh * 4 + i) * 16 + lg * 4;
            #pragma unroll
            for (int kt = 0; kt < 4; ++kt) {
                f32x4 acc = __builtin_amdgcn_mfma_f32_16x16x32_bf16(
                    afr[mh * 4 + i], bfr[kt], (f32x4){0.f, 0.f, 0.f, 0.f}, 0, 0, 0);
                const int k = kt * 16 + li;
                if (k < K1) {
                    #pragma unroll
                    for (int q = 0; q < 4; ++q)
                        stg[rloc][(mbase + q) * K1 + k] = acc[q] + bias[kt];
                } else if (k < KT) {
                    #pragma unroll
                    for (int q = 0; q < 4; ++q)
                        stg[rloc][OUT1_ROW + (mbase + q) * K2 + (k - K1)] = acc[q] + bias[kt];
                }
            }
        }
        __syncthreads();

        // coalesced copyout of this half's 2 rows
        #pragma unroll
        for (int rr = 0; rr < 2; ++rr) {
            const int row = row0 + h * 2 + rr;
            float* o1 = out + (size_t)row * OUT1_ROW;
            float* o2 = out + (size_t)ROWS * OUT1_ROW + (size_t)row * OUT2_ROW;
            const float4* s1 = (const float4*)stg[rr];
            const float4* s2 = (const float4*)(stg[rr] + OUT1_ROW);
            for (int i4 = t; i4 < OUT1_ROW / 4; i4 += 256)
                ((float4*)o1)[i4] = s1[i4];
            for (int i4 = t; i4 < OUT2_ROW / 4; i4 += 256)
                ((float4*)o2)[i4] = s2[i4];
        }
        if (h == 0) __syncthreads();   // stg reused by half 1
    }
}

extern "C" void kernel_launch(void* const* d_in, const int* in_sizes, int n_in,
                              void* d_out, int out_size, void* d_ws, size_t ws_size,
                              hipStream_t stream) {
    const float* z    = (const float*)d_in[0];
    const float* W_in = (const float*)d_in[1];
    const float* b_in = (const float*)d_in[2];
    const float* ln_g = (const float*)d_in[3];
    const float* ln_b = (const float*)d_in[4];
    const float* W1   = (const float*)d_in[5];
    const float* b1   = (const float*)d_in[6];
    const float* W2   = (const float*)d_in[7];
    const float* b2   = (const float*)d_in[8];
    float* out = (float*)d_out;

    unsigned short* af  = (unsigned short*)d_ws;   // 32768 hw (64 KB)
    unsigned short* bbf = af + 32768;              // 32768 hw (64 KB)
    unsigned short* Wf  = bbf + 32768;             // 53248 hw (104 KB)

    ln_wprep_kernel<<<269, 256, 0, stream>>>(z, W_in, b_in, ln_g, ln_b,
                                             W1, W2, af, bbf, Wf);
    pair_fused_kernel<<<256, 256, 0, stream>>>(af, bbf, Wf, b1, b2, out);
}

// Round 8
// 30.134 us; speedup vs baseline: 1.4027x; 1.4027x over previous
//
#include <hip/hip_runtime.h>
#include <hip/hip_bf16.h>
#include <math.h>

#define NB 8
#define NL 128
#define D_ATOM 256
#define DH 32       // d_hid
#define DAB 64      // 2*d_hid
#define K1 21
#define K2 30
#define KT 51       // K1+K2
#define ROWS (NB*NL) // 1024
#define LN_EPS 1e-5f

#define OUT1_ROW (NL*K1)      // 2688 floats
#define OUT2_ROW (NL*K2)      // 3840 floats
#define STAGE_N  (OUT1_ROW + OUT2_ROW) // 6528 floats

typedef __attribute__((ext_vector_type(8))) short bf16x8;
typedef __attribute__((ext_vector_type(4))) float f32x4;

__device__ __forceinline__ unsigned short f2bf(float x) {
    __hip_bfloat16 h = __float2bfloat16(x);
    return *reinterpret_cast<unsigned short*>(&h);
}

// ---------------- Kernel 1: LN (blocks 0..255) + W-prep (blocks 256..268) ----
// (verified in rounds 6/7, unchanged)
__global__ __launch_bounds__(256) void ln_wprep_kernel(
    const float* __restrict__ z, const float* __restrict__ W_in,
    const float* __restrict__ b_in, const float* __restrict__ ln_g,
    const float* __restrict__ ln_b, const float* __restrict__ W1,
    const float* __restrict__ W2, unsigned short* __restrict__ af,
    unsigned short* __restrict__ bbf, unsigned short* __restrict__ Wf)
{
    const int t = threadIdx.x;

    if (blockIdx.x >= 256) {
        const int base = ((int)blockIdx.x - 256) * 4096;
        #pragma unroll
        for (int e = 0; e < 16; ++e) {
            int widx = base + e * 256 + t;
            int nt = widx >> 9, lane = (widx >> 3) & 63, reg = widx & 7;
            int dk = nt * 16 + (lane & 15);
            int c  = ((lane >> 4) << 3) + reg;
            int d  = dk / 52, k = dk - d * 52;
            float v = 0.f;
            if (k < K1)      v = W1[(c * DH + d) * K1 + k];
            else if (k < KT) v = W2[(c * DH + d) * K2 + (k - K1)];
            Wf[widx] = f2bf(v);
        }
        return;
    }

    __shared__ float Wl[D_ATOM * DAB];   // 64 KB
    __shared__ float zl[4][D_ATOM];      // 4 KB
    const int w = t >> 6, j = t & 63;
    const int row0 = blockIdx.x * 4;

    #pragma unroll
    for (int s = 0; s < 16; ++s) {
        int i4 = t + s * 256;
        ((float4*)Wl)[i4] = ((const float4*)W_in)[i4];
    }
    ((float4*)zl)[t] = ((const float4*)(z + (size_t)row0 * D_ATOM))[t];
    __syncthreads();

    float acc = b_in[j];
    #pragma unroll 8
    for (int i = 0; i < D_ATOM; ++i)
        acc = fmaf(zl[w][i], Wl[i * DAB + j], acc);

    float g = 0.5f * acc * (1.0f + erff(acc * 0.70710678118654752f));

    float s = g, sq = g * g;
    #pragma unroll
    for (int msk = 1; msk < 64; msk <<= 1) {
        s  += __shfl_xor(s,  msk, 64);
        sq += __shfl_xor(sq, msk, 64);
    }
    float mu  = s  * (1.0f / 64.0f);
    float var = sq * (1.0f / 64.0f) - mu * mu;
    float y = (g - mu) * rsqrtf(var + LN_EPS) * ln_g[j] + ln_b[j];

    const int row = row0 + w;
    unsigned short hv = f2bf(y);
    if (j < DH) {
        const int c = j;
        af[((row >> 4) << 9) + ((((row & 15) | ((c >> 3) << 4)) << 3) | (c & 7))] = hv;
    } else {
        const int d = j - DH, m = row & 127, batch = row >> 7;
        bbf[batch * 4096 + ((m >> 4) << 9) +
            ((((m & 15) | ((d >> 3) << 4)) << 3) | (d & 7))] = hv;
    }
}

// ---------------- Kernel 2: pair product (round-5 structure, MFMA phase A) ----
// 2 rows per block, 512 blocks, 59 KB LDS -> 2 blocks/CU, 8 waves/CU.
// Phase A: T = a @ W via MFMA over Wf ntiles (replaces round-5 VALU GEMV);
//          block keeps its 2 rows (uniform q-select) -> Tf LDS (B-frag order).
// Phase B: round-5 verified: 16 MFMA/wave from bbf A-frags x Tf B-frags.
// Phase C: round-5 verified: stage + coalesced float4 copyout.
__global__ __launch_bounds__(256) void pair_mfma_kernel(
    const unsigned short* __restrict__ af, const unsigned short* __restrict__ bbf,
    const unsigned short* __restrict__ Wf, const float* __restrict__ b1v,
    const float* __restrict__ b2v, float* __restrict__ out)
{
    const int row0  = blockIdx.x * 2;
    const int batch = row0 >> 7;
    const int t     = threadIdx.x;
    const int w     = t >> 6, l = t & 63;
    const int lg    = l >> 4, li = l & 15;

    __shared__ unsigned short Tf[2 * 4 * 64 * 8];    // 8 KB (B-fragments, 2 rows)
    __shared__ __align__(16) float stg[2][STAGE_N];  // 51 KB

    // zero-init Tf (pad cols k=51..63 must be 0)
    #pragma unroll
    for (int s = 0; s < 8; ++s)
        ((unsigned int*)Tf)[t + s * 256] = 0u;

    const int mt = row0 >> 4;            // row-mtile containing our 2 rows
    const int r0 = row0 & 15;
    const int g  = r0 >> 2;              // lane-group holding rows r0, r0+1
    const bool qhi = (r0 & 3) == 2;      // rows are q={2,3} of the group (else {0,1})

    const bf16x8 a = ((const bf16x8*)af)[mt * 64 + l];
    __syncthreads();

    // ---- phase A: T tiles via MFMA, keep 2 rows, scatter to Tf ----
    #pragma unroll 4
    for (int i = 0; i < 26; ++i) {
        const int nt = w * 26 + i;
        const bf16x8 bw = ((const bf16x8*)Wf)[nt * 64 + l];
        f32x4 c = __builtin_amdgcn_mfma_f32_16x16x32_bf16(
            a, bw, (f32x4){0.f, 0.f, 0.f, 0.f}, 0, 0, 0);
        if (lg == g) {
            const int dk = nt * 16 + li;
            const int d  = dk / 52;
            const int k  = dk - d * 52;
            if (k < KT) {
                const int fidx = ((k >> 4) * 64 + ((k & 15) | ((d >> 3) << 4))) * 8
                                 + (d & 7);
                float v0 = qhi ? c[2] : c[0];
                float v1 = qhi ? c[3] : c[1];
                Tf[fidx]        = f2bf(v0);
                Tf[2048 + fidx] = f2bf(v1);
            }
        }
    }
    __syncthreads();

    // ---- phase B: pair MFMA (verbatim round 5) ----
    const int r  = w >> 1;            // row within pair
    const int mh = w & 1;             // m-half

    bf16x8 afr[4], bfr[4];
    #pragma unroll
    for (int i = 0; i < 4; ++i)
        afr[i] = ((const bf16x8*)bbf)[batch * 512 + (mh * 4 + i) * 64 + l];
    #pragma unroll
    for (int kt = 0; kt < 4; ++kt)
        bfr[kt] = ((const bf16x8*)Tf)[(r * 4 + kt) * 64 + l];

    float bias[4];
    #pragma unroll
    for (int kt = 0; kt < 4; ++kt) {
        int k = kt * 16 + li;
        bias[kt] = (k < K1) ? b1v[k] : (k < KT ? b2v[k - K1] : 0.f);
    }

    #pragma unroll
    for (int i = 0; i < 4; ++i) {
        const int mbase = (mh * 4 + i) * 16 + lg * 4;
        #pragma unroll
        for (int kt = 0; kt < 4; ++kt) {
            f32x4 acc = __builtin_amdgcn_mfma_f32_16x16x32_bf16(
                afr[i], bfr[kt], (f32x4){0.f, 0.f, 0.f, 0.f}, 0, 0, 0);
            const int k = kt * 16 + li;
            if (k < K1) {
                #pragma unroll
                for (int q = 0; q < 4; ++q)
                    stg[r][(mbase + q) * K1 + k] = acc[q] + bias[kt];
            } else if (k < KT) {
                #pragma unroll
                for (int q = 0; q < 4; ++q)
                    stg[r][OUT1_ROW + (mbase + q) * K2 + (k - K1)] = acc[q] + bias[kt];
            }
        }
    }
    __syncthreads();

    // ---- phase C: coalesced copy-out of both rows (verbatim round 5) ----
    #pragma unroll
    for (int rr = 0; rr < 2; ++rr) {
        const int row = row0 + rr;
        float* o1 = out + (size_t)row * OUT1_ROW;
        float* o2 = out + (size_t)ROWS * OUT1_ROW + (size_t)row * OUT2_ROW;
        const float4* s1 = (const float4*)stg[rr];
        const float4* s2 = (const float4*)(stg[rr] + OUT1_ROW);
        for (int i4 = t; i4 < OUT1_ROW / 4; i4 += 256)
            ((float4*)o1)[i4] = s1[i4];
        for (int i4 = t; i4 < OUT2_ROW / 4; i4 += 256)
            ((float4*)o2)[i4] = s2[i4];
    }
}

extern "C" void kernel_launch(void* const* d_in, const int* in_sizes, int n_in,
                              void* d_out, int out_size, void* d_ws, size_t ws_size,
                              hipStream_t stream) {
    const float* z    = (const float*)d_in[0];
    const float* W_in = (const float*)d_in[1];
    const float* b_in = (const float*)d_in[2];
    const float* ln_g = (const float*)d_in[3];
    const float* ln_b = (const float*)d_in[4];
    const float* W1   = (const float*)d_in[5];
    const float* b1   = (const float*)d_in[6];
    const float* W2   = (const float*)d_in[7];
    const float* b2   = (const float*)d_in[8];
    float* out = (float*)d_out;

    unsigned short* af  = (unsigned short*)d_ws;   // 32768 hw (64 KB)
    unsigned short* bbf = af + 32768;              // 32768 hw (64 KB)
    unsigned short* Wf  = bbf + 32768;             // 53248 hw (104 KB)

    ln_wprep_kernel<<<269, 256, 0, stream>>>(z, W_in, b_in, ln_g, ln_b,
                                             W1, W2, af, bbf, Wf);
    pair_mfma_kernel<<<ROWS / 2, 256, 0, stream>>>(af, bbf, Wf, b1, b2, out);
}

// Round 9
// 26.654 us; speedup vs baseline: 1.5858x; 1.1306x over previous
//
#include <hip/hip_runtime.h>
#include <hip/hip_bf16.h>
#include <math.h>

#define NB 8
#define NL 128
#define D_ATOM 256
#define DH 32       // d_hid
#define DAB 64      // 2*d_hid
#define K1 21
#define K2 30
#define KT 51       // K1+K2
#define ROWS (NB*NL) // 1024
#define LN_EPS 1e-5f

#define OUT1_ROW (NL*K1)      // 2688 floats
#define OUT2_ROW (NL*K2)      // 3840 floats
#define STAGE_N  (OUT1_ROW + OUT2_ROW) // 6528 floats
#define TROW_HW 2048          // per-row T fragments: 4 kt * 512 hw

typedef __attribute__((ext_vector_type(8))) short bf16x8;
typedef __attribute__((ext_vector_type(4))) float f32x4;

__device__ __forceinline__ unsigned short f2bf(float x) {
    __hip_bfloat16 h = __float2bfloat16(x);
    return *reinterpret_cast<unsigned short*>(&h);
}

// ---------------- Kernel 1: LN + T-GEMV ----------------
// 4 rows per block, 256 blocks.
// LN (verified): ab = LN(gelu(z@W_in+b_in)). b-half -> bbf global (A-frag u16).
// a-half -> LDS (f32). Then T[4 rows] = a @ Wcat via VALU GEMV (7 coalesced
// W-read streams, 4 row-accs each), written to T_ws in B-fragment order.
__global__ __launch_bounds__(256) void ln_t_kernel(
    const float* __restrict__ z, const float* __restrict__ W_in,
    const float* __restrict__ b_in, const float* __restrict__ ln_g,
    const float* __restrict__ ln_b, const float* __restrict__ W1,
    const float* __restrict__ W2, unsigned short* __restrict__ bbf,
    unsigned short* __restrict__ T_ws)
{
    __shared__ float Wl[D_ATOM * DAB];   // 64 KB
    __shared__ float zl[4][D_ATOM];      // 4 KB
    __shared__ float al[4][DH];          // a rows, f32
    const int t = threadIdx.x;
    const int w = t >> 6, j = t & 63;
    const int row0 = blockIdx.x * 4;

    #pragma unroll
    for (int s = 0; s < 16; ++s) {
        int i4 = t + s * 256;
        ((float4*)Wl)[i4] = ((const float4*)W_in)[i4];
    }
    ((float4*)zl)[t] = ((const float4*)(z + (size_t)row0 * D_ATOM))[t];
    __syncthreads();

    float acc = b_in[j];
    #pragma unroll 8
    for (int i = 0; i < D_ATOM; ++i)
        acc = fmaf(zl[w][i], Wl[i * DAB + j], acc);

    float g = 0.5f * acc * (1.0f + erff(acc * 0.70710678118654752f));

    float s = g, sq = g * g;
    #pragma unroll
    for (int msk = 1; msk < 64; msk <<= 1) {
        s  += __shfl_xor(s,  msk, 64);
        sq += __shfl_xor(sq, msk, 64);
    }
    float mu  = s  * (1.0f / 64.0f);
    float var = sq * (1.0f / 64.0f) - mu * mu;
    float y = (g - mu) * rsqrtf(var + LN_EPS) * ln_g[j] + ln_b[j];

    const int row = row0 + w;
    if (j < DH) {
        al[w][j] = y;                    // a stays in-block (f32)
    } else {
        const int d = j - DH, m = row & 127, batch = row >> 7;
        bbf[batch * 4096 + ((m >> 4) << 9) +
            ((((m & 15) | ((d >> 3) << 4)) << 3) | (d & 7))] = f2bf(y);
    }
    __syncthreads();

    // ---- T GEMV: T[rr][d][k] = sum_c al[rr][c] * Wcat[c][d][k] ----
    float tacc[7][4];
    const float* wptr[7];
    int wstr[7], fidx[7];
    bool val[7];
    #pragma unroll
    for (int s2 = 0; s2 < 7; ++s2) {
        int o = t + s2 * 256;
        val[s2] = (o < 1632);
        int oo = val[s2] ? o : 0;
        int d, k;
        if (oo < 672) {
            wptr[s2] = W1 + oo; wstr[s2] = 672;
            d = oo / 21; k = oo % 21;
        } else {
            int o2 = oo - 672;
            wptr[s2] = W2 + o2; wstr[s2] = 960;
            d = o2 / 30; k = 21 + o2 % 30;
        }
        fidx[s2] = ((k >> 4) << 9) + ((((k & 15) | ((d >> 3) << 4)) << 3) | (d & 7));
        #pragma unroll
        for (int rr = 0; rr < 4; ++rr) tacc[s2][rr] = 0.f;
    }
    #pragma unroll 4
    for (int c = 0; c < DH; ++c) {
        float a0 = al[0][c], a1 = al[1][c], a2 = al[2][c], a3 = al[3][c];
        #pragma unroll
        for (int s2 = 0; s2 < 7; ++s2) {
            float wv = wptr[s2][c * wstr[s2]];
            tacc[s2][0] = fmaf(a0, wv, tacc[s2][0]);
            tacc[s2][1] = fmaf(a1, wv, tacc[s2][1]);
            tacc[s2][2] = fmaf(a2, wv, tacc[s2][2]);
            tacc[s2][3] = fmaf(a3, wv, tacc[s2][3]);
        }
    }
    #pragma unroll
    for (int s2 = 0; s2 < 7; ++s2) {
        if (val[s2]) {
            #pragma unroll
            for (int rr = 0; rr < 4; ++rr)
                T_ws[(size_t)(row0 + rr) * TROW_HW + fidx[s2]] = f2bf(tacc[s2][rr]);
        }
    }
}

// ---------------- Kernel 2: pair product (pure MFMA + copyout) ----------------
// 2 rows per block, 512 blocks. LDS = stg only (51 KB) -> 3 blocks/CU.
// Fragments loaded straight from ws (coalesced 16B/lane); kt=3 pad lanes
// (k>=51) masked to zero in-register (deterministic, no pad writes needed).
__global__ __launch_bounds__(256) void pair_kernel(
    const unsigned short* __restrict__ bbf, const unsigned short* __restrict__ T_ws,
    const float* __restrict__ b1v, const float* __restrict__ b2v,
    float* __restrict__ out)
{
    const int row0  = blockIdx.x * 2;
    const int batch = row0 >> 7;
    const int t     = threadIdx.x;
    const int w = t >> 6, l = t & 63;
    const int lg = l >> 4, li = l & 15;
    const int r = w >> 1;               // row within pair
    const int mh = w & 1;               // m-half

    __shared__ __align__(16) float stg[2][STAGE_N];   // 51 KB

    bf16x8 afr[4], bfr[4];
    #pragma unroll
    for (int i = 0; i < 4; ++i)
        afr[i] = ((const bf16x8*)bbf)[batch * 512 + (mh * 4 + i) * 64 + l];
    #pragma unroll
    for (int kt = 0; kt < 4; ++kt)
        bfr[kt] = ((const bf16x8*)T_ws)[(size_t)(row0 + r) * 256 + kt * 64 + l];

    // kt=3 tile: lanes with k = 48+li >= 51 hold unwritten ws -> zero them.
    if (li >= 3) {
        bf16x8 zz = {0, 0, 0, 0, 0, 0, 0, 0};
        bfr[3] = zz;
    }

    float bias[4];
    #pragma unroll
    for (int kt = 0; kt < 4; ++kt) {
        int k = kt * 16 + li;
        bias[kt] = (k < K1) ? b1v[k] : (k < KT ? b2v[k - K1] : 0.f);
    }

    #pragma unroll
    for (int i = 0; i < 4; ++i) {
        const int mbase = (mh * 4 + i) * 16 + lg * 4;
        #pragma unroll
        for (int kt = 0; kt < 4; ++kt) {
            f32x4 acc = __builtin_amdgcn_mfma_f32_16x16x32_bf16(
                afr[i], bfr[kt], (f32x4){0.f, 0.f, 0.f, 0.f}, 0, 0, 0);
            const int k = kt * 16 + li;
            if (k < K1) {
                #pragma unroll
                for (int q = 0; q < 4; ++q)
                    stg[r][(mbase + q) * K1 + k] = acc[q] + bias[kt];
            } else if (k < KT) {
                #pragma unroll
                for (int q = 0; q < 4; ++q)
                    stg[r][OUT1_ROW + (mbase + q) * K2 + (k - K1)] = acc[q] + bias[kt];
            }
        }
    }
    __syncthreads();

    #pragma unroll
    for (int rr = 0; rr < 2; ++rr) {
        const int row = row0 + rr;
        float* o1 = out + (size_t)row * OUT1_ROW;
        float* o2 = out + (size_t)ROWS * OUT1_ROW + (size_t)row * OUT2_ROW;
        const float4* s1 = (const float4*)stg[rr];
        const float4* s2 = (const float4*)(stg[rr] + OUT1_ROW);
        for (int i4 = t; i4 < OUT1_ROW / 4; i4 += 256)
            ((float4*)o1)[i4] = s1[i4];
        for (int i4 = t; i4 < OUT2_ROW / 4; i4 += 256)
            ((float4*)o2)[i4] = s2[i4];
    }
}

extern "C" void kernel_launch(void* const* d_in, const int* in_sizes, int n_in,
                              void* d_out, int out_size, void* d_ws, size_t ws_size,
                              hipStream_t stream) {
    const float* z    = (const float*)d_in[0];
    const float* W_in = (const float*)d_in[1];
    const float* b_in = (const float*)d_in[2];
    const float* ln_g = (const float*)d_in[3];
    const float* ln_b = (const float*)d_in[4];
    const float* W1   = (const float*)d_in[5];
    const float* b1   = (const float*)d_in[6];
    const float* W2   = (const float*)d_in[7];
    const float* b2   = (const float*)d_in[8];
    float* out = (float*)d_out;

    unsigned short* bbf  = (unsigned short*)d_ws;   // 32768 hw (64 KB)
    unsigned short* T_ws = bbf + 32768;             // 1024*2048 hw (4 MB)

    ln_t_kernel<<<256, 256, 0, stream>>>(z, W_in, b_in, ln_g, ln_b,
                                         W1, W2, bbf, T_ws);
    pair_kernel<<<ROWS / 2, 256, 0, stream>>>(bbf, T_ws, b1, b2, out);
}